// Round 2
// baseline (730.769 us; speedup 1.0000x reference)
//
#include <hip/hip_runtime.h>
#include <math.h>

#define EMBED 1536
#define BN 64
#define XS_STRIDE 1544   // shorts; row stride 3088 B -> 16B aligned (ds_read_b128 ok)
#define GS_STRIDE 80     // shorts; row stride 160 B -> 16B aligned
#define NT_GRID 768      // persistent blocks: 3 per CU (LDS-capped) x 256 CUs

typedef __attribute__((ext_vector_type(8))) short short8;
typedef __attribute__((ext_vector_type(4))) float f32x4;

__device__ inline unsigned short f2bf(float f) {
    union { float f; unsigned u; } c; c.f = f;
    unsigned u = c.u;
    return (unsigned short)((u + 0x7fffu + ((u >> 16) & 1u)) >> 16);
}
__device__ inline float bf2f(unsigned short h) {
    union { unsigned u; float f; } c; c.u = ((unsigned)h) << 16;
    return c.f;
}

// Prep (one kernel): wdg[b][d]=bf16(w_down*gamma), wub=bf16(w_up), c1/c2 reductions, queue init.
__global__ void prep_kernel(const float* __restrict__ w_down, const float* __restrict__ w_up,
                            const float* __restrict__ gamma, const float* __restrict__ beta,
                            unsigned short* __restrict__ wdg, unsigned short* __restrict__ wub,
                            float* __restrict__ c1, float* __restrict__ c2,
                            int* __restrict__ cnt, int cnt_init) {
    int blk = blockIdx.x;
    if (blk == 0 && threadIdx.x == 0) *cnt = cnt_init;  // work-queue head (reset every launch)
    if (blk < 384) {
        int i = blk * 256 + threadIdx.x;          // < 64*1536
        int d = i % EMBED;
        wdg[i] = f2bf(w_down[i] * gamma[d]);      // fold LN gamma into down-weights
        wub[i] = f2bf(w_up[i]);
        return;
    }
    int b = blk - 384;                            // 0..63
    int t = threadIdx.x;
    float s1 = 0.f, s2 = 0.f;
    for (int d = t; d < EMBED; d += 256) {
        float w = w_down[b * EMBED + d];
        s1 += gamma[d] * w;
        s2 += beta[d] * w;
    }
    #pragma unroll
    for (int m = 1; m < 64; m <<= 1) { s1 += __shfl_xor(s1, m); s2 += __shfl_xor(s2, m); }
    __shared__ float r1[4], r2[4];
    int wave = t >> 6, lane = t & 63;
    if (lane == 0) { r1[wave] = s1; r2[wave] = s2; }
    __syncthreads();
    if (t == 0) {
        c1[b] = r1[0] + r1[1] + r1[2] + r1[3];
        c2[b] = r2[0] + r2[1] + r2[2] + r2[3];
    }
}

// Persistent fused kernel: LN-stats + down-proj(MFMA) + GELU + up-proj(MFMA) + L2-normalize.
// 16 rows/tile, 256 threads (4 waves), dynamic tile queue. Each iteration issues the NEXT
// tile's 24 float4 global loads per wave before GEMM1, so HBM reads stay in flight through
// the compute phases (latency-bound fix: sustain ~4.6 KB/CU outstanding instead of a burst).
// LDS ~52 KB -> 3 blocks/CU. launch_bounds(256,3): reg cap ~682/wave, no clamp pressure.
__global__ __launch_bounds__(256, 3) void fused_kernel(
    const float* __restrict__ x, const float* __restrict__ b_down,
    const float* __restrict__ b_up,
    const unsigned short* __restrict__ wdg, const unsigned short* __restrict__ wub,
    const float* __restrict__ c1, const float* __restrict__ c2,
    float* __restrict__ out, int* __restrict__ cnt, int ntiles)
{
    __shared__ unsigned short xs[16 * XS_STRIDE];  // bf16(x): GEMM1 A-operand AND GEMM2 residual
    __shared__ unsigned short gs[16 * GS_STRIDE];  // bf16 gelu output [token][b]
    __shared__ float mean_s[16], rstd_s[16], sumsq_s[2][16];
    __shared__ int tile_s;

    const int tid  = threadIdx.x;
    const int wave = tid >> 6, lane = tid & 63;
    const int l16  = lane & 15, quad = lane >> 4;

    int tcur = blockIdx.x;                         // initial tile; queue starts at gridDim
    float4 v[4][6];                                // 4 rows/wave, 24 outstanding float4 loads
    {
        const long row0 = (long)tcur * 16;
        #pragma unroll
        for (int j = 0; j < 4; ++j) {
            const float4* xp = (const float4*)(x + (row0 + wave * 4 + j) * EMBED);
            #pragma unroll
            for (int k = 0; k < 6; ++k) v[j][k] = xp[lane + 64 * k];
        }
    }

    int parity = 0;
    for (;;) {
        // ---- Phase A: stats + stage bf16(x) into xs ----
        #pragma unroll
        for (int j = 0; j < 4; ++j) {
            int lr = wave * 4 + j;
            float s = 0.f, ss = 0.f;
            #pragma unroll
            for (int k = 0; k < 6; ++k) {
                s  += v[j][k].x + v[j][k].y + v[j][k].z + v[j][k].w;
                ss += v[j][k].x * v[j][k].x + v[j][k].y * v[j][k].y
                    + v[j][k].z * v[j][k].z + v[j][k].w * v[j][k].w;
            }
            #pragma unroll
            for (int m = 1; m < 64; m <<= 1) { s += __shfl_xor(s, m); ss += __shfl_xor(ss, m); }
            float mean = s * (1.f / EMBED);
            float var  = ss * (1.f / EMBED) - mean * mean;
            if (lane == 0) {
                mean_s[lr] = mean;
                rstd_s[lr] = rsqrtf(var + 1e-5f);
                sumsq_s[parity][lr] = 0.f;
            }
            #pragma unroll
            for (int k = 0; k < 6; ++k) {
                ushort4 p;
                p.x = f2bf(v[j][k].x); p.y = f2bf(v[j][k].y);
                p.z = f2bf(v[j][k].z); p.w = f2bf(v[j][k].w);
                *(ushort4*)(&xs[lr * XS_STRIDE + 4 * (lane + 64 * k)]) = p;
            }
        }
        if (tid == 0) tile_s = atomicAdd(cnt, 1);
        __syncthreads();  // B1: xs staged, tile_s broadcast

        const int tnext = tile_s;
        const bool have_next = (tnext < ntiles);
        if (have_next) {  // prefetch next tile while GEMM1/GEMM2 run
            const long row0 = (long)tnext * 16;
            #pragma unroll
            for (int j = 0; j < 4; ++j) {
                const float4* xp = (const float4*)(x + (row0 + wave * 4 + j) * EMBED);
                #pragma unroll
                for (int k = 0; k < 6; ++k) v[j][k] = xp[lane + 64 * k];
            }
        }

        // ---- GEMM1: t[token 16][b 16/wave] = x . (gamma*w_down)^T, K=1536 ----
        f32x4 acc = {0.f, 0.f, 0.f, 0.f};
        {
            const unsigned short* arow = &xs[l16 * XS_STRIDE];                    // A[m=l16][k]
            const unsigned short* brow = wdg + (size_t)(wave * 16 + l16) * EMBED; // B^T: W[b=l16][k]
            #pragma unroll 4
            for (int kk = 0; kk < 48; ++kk) {
                int ko = kk * 32 + quad * 8;
                short8 a = *(const short8*)(arow + ko);
                short8 b = *(const short8*)(brow + ko);
                acc = __builtin_amdgcn_mfma_f32_16x16x32_bf16(a, b, acc, 0, 0, 0);
            }
        }
        // epilogue: LN scalar corrections + bias + exact GELU -> gs[token][b]
        {
            int bg = wave * 16 + l16;  // D col = lane&15
            float c1v = c1[bg], c2v = c2[bg], bdv = b_down[bg];
            #pragma unroll
            for (int reg = 0; reg < 4; ++reg) {
                int r = quad * 4 + reg;  // D row = (lane>>4)*4 + reg
                float rs = rstd_s[r];
                float vv = rs * acc[reg] - rs * mean_s[r] * c1v + c2v + bdv;
                float g = 0.5f * vv * (1.f + erff(vv * 0.70710678118654752f));
                gs[r * GS_STRIDE + bg] = f2bf(g);
            }
        }
        __syncthreads();  // B2: gs ready (drains prefetch loads too; overlapped with GEMM1)

        // ---- GEMM2 (transposed tile): D[m=d 16][n=token 16] = w_up_tile . g^T + (x + b_up) ----
        short8 gb0 = *(const short8*)(&gs[l16 * GS_STRIDE + quad * 8]);
        short8 gb1 = *(const short8*)(&gs[l16 * GS_STRIDE + 32 + quad * 8]);
        const int dbase = wave * 384;
        f32x4 cc[24];
        float sqs = 0.f;
        #pragma unroll
        for (int t = 0; t < 24; ++t) {
            int d0 = dbase + t * 16;
            int dm = d0 + quad * 4;                                  // C rows: 4 consecutive d
            float4 bu = *(const float4*)(b_up + dm);
            ushort4 rx = *(const ushort4*)(&xs[l16 * XS_STRIDE + dm]); // residual: token l16
            f32x4 c;
            c[0] = bf2f(rx.x) + bu.x;
            c[1] = bf2f(rx.y) + bu.y;
            c[2] = bf2f(rx.z) + bu.z;
            c[3] = bf2f(rx.w) + bu.w;
            const unsigned short* wrow = wub + (size_t)(d0 + l16) * 64;  // A[m=l16][k]
            short8 a0 = *(const short8*)(wrow + quad * 8);
            short8 a1 = *(const short8*)(wrow + 32 + quad * 8);
            c = __builtin_amdgcn_mfma_f32_16x16x32_bf16(a0, gb0, c, 0, 0, 0);
            c = __builtin_amdgcn_mfma_f32_16x16x32_bf16(a1, gb1, c, 0, 0, 0);
            cc[t] = c;
            sqs += c[0] * c[0] + c[1] * c[1] + c[2] * c[2] + c[3] * c[3];
        }
        sqs += __shfl_xor(sqs, 16);
        sqs += __shfl_xor(sqs, 32);
        if (lane < 16) atomicAdd(&sumsq_s[parity][l16], sqs);
        __syncthreads();  // B3: sumsq ready; also all xs/gs reads of this tile complete

        const float inv = 1.f / fmaxf(sqrtf(sumsq_s[parity][l16]), 1e-12f);
        float* orow = out + ((long)tcur * 16 + l16) * EMBED;
        #pragma unroll
        for (int t = 0; t < 24; ++t) {
            int dm = dbase + t * 16 + quad * 4;
            f32x4 c = cc[t];
            float4 o;
            o.x = c[0] * inv; o.y = c[1] * inv; o.z = c[2] * inv; o.w = c[3] * inv;
            *(float4*)(orow + dm) = o;   // 16 B/lane store
        }

        if (!have_next) break;
        tcur = tnext;
        parity ^= 1;
        // next Phase A overwrites xs/mean_s: safe, all readers passed B3.
    }
}

extern "C" void kernel_launch(void* const* d_in, const int* in_sizes, int n_in,
                              void* d_out, int out_size, void* d_ws, size_t ws_size,
                              hipStream_t stream)
{
    const float* x      = (const float*)d_in[0];
    const float* w_down = (const float*)d_in[1];
    const float* b_down = (const float*)d_in[2];
    const float* w_up   = (const float*)d_in[3];
    const float* b_up   = (const float*)d_in[4];
    const float* gamma  = (const float*)d_in[5];
    const float* beta   = (const float*)d_in[6];
    float* out = (float*)d_out;

    const int N = in_sizes[0] / EMBED;  // 32768, multiple of 16
    const int ntiles = N / 16;
    const int grid = ntiles < NT_GRID ? ntiles : NT_GRID;

    unsigned short* wdg = (unsigned short*)d_ws;
    unsigned short* wub = wdg + BN * EMBED;
    float* c1 = (float*)(wub + BN * EMBED);
    float* c2 = c1 + BN;
    int* cnt  = (int*)(c2 + BN);

    prep_kernel<<<384 + BN, 256, 0, stream>>>(w_down, w_up, gamma, beta, wdg, wub, c1, c2,
                                              cnt, grid);
    fused_kernel<<<grid, 256, 0, stream>>>(x, b_down, b_up, wdg, wub, c1, c2, out, cnt, ntiles);
}

// Round 3
// 720.606 us; speedup vs baseline: 1.0141x; 1.0141x over previous
//
#include <hip/hip_runtime.h>
#include <math.h>

#define EMBED 1536
#define BN 64
#define XS_STRIDE 1544   // shorts; row stride 3088 B -> 16B aligned (ds_read_b128 ok)
#define GS_STRIDE 80     // shorts; row stride 160 B -> 16B aligned
#define NT_GRID 768      // persistent blocks: 3 per CU (LDS-capped) x 256 CUs

typedef __attribute__((ext_vector_type(8))) short short8;
typedef __attribute__((ext_vector_type(4))) float f32x4;

__device__ inline unsigned short f2bf(float f) {
    union { float f; unsigned u; } c; c.f = f;
    unsigned u = c.u;
    return (unsigned short)((u + 0x7fffu + ((u >> 16) & 1u)) >> 16);
}
__device__ inline float bf2f(unsigned short h) {
    union { unsigned u; float f; } c; c.u = ((unsigned)h) << 16;
    return c.f;
}

// Prep: wdg=bf16(w_down*gamma), wub=bf16(w_up), wut=bf16(w_up^T), Mb=bf16(w_up^T w_up),
//       c1[b]=sum gamma*w_down, c2[b]=sum beta*w_down, c3[b]=sum w_up[:,b]*b_up, queue init.
__global__ void prep_kernel(const float* __restrict__ w_down, const float* __restrict__ w_up,
                            const float* __restrict__ gamma, const float* __restrict__ beta,
                            const float* __restrict__ b_up,
                            unsigned short* __restrict__ wdg, unsigned short* __restrict__ wub,
                            unsigned short* __restrict__ wut, unsigned short* __restrict__ Mb,
                            float* __restrict__ c1, float* __restrict__ c2,
                            float* __restrict__ c3, int* __restrict__ cnt, int cnt_init) {
    int blk = blockIdx.x;
    int t = threadIdx.x;
    if (blk == 0 && t == 0) *cnt = cnt_init;  // work-queue head (reset every launch)
    if (blk < 384) {
        int i = blk * 256 + t;                // < 64*1536
        int d = i % EMBED;
        wdg[i] = f2bf(w_down[i] * gamma[d]);  // fold LN gamma into down-weights
        wub[i] = f2bf(w_up[i]);
        int b2 = i / EMBED, d2 = i - b2 * EMBED;
        wut[i] = f2bf(w_up[d2 * BN + b2]);    // wut[b][d] = w_up[d][b]
        return;
    }
    if (blk < 448) {
        int b = blk - 384;                    // 0..63
        float s1 = 0.f, s2 = 0.f, s3 = 0.f;
        for (int d = t; d < EMBED; d += 256) {
            float w = w_down[b * EMBED + d];
            s1 += gamma[d] * w;
            s2 += beta[d] * w;
            s3 += w_up[d * BN + b] * b_up[d];
        }
        #pragma unroll
        for (int m = 1; m < 64; m <<= 1) {
            s1 += __shfl_xor(s1, m); s2 += __shfl_xor(s2, m); s3 += __shfl_xor(s3, m);
        }
        __shared__ float r1[4], r2[4], r3[4];
        int wave = t >> 6, lane = t & 63;
        if (lane == 0) { r1[wave] = s1; r2[wave] = s2; r3[wave] = s3; }
        __syncthreads();
        if (t == 0) {
            c1[b] = r1[0] + r1[1] + r1[2] + r1[3];
            c2[b] = r2[0] + r2[1] + r2[2] + r2[3];
            c3[b] = r3[0] + r3[1] + r3[2] + r3[3];
        }
        return;
    }
    // Mb blocks (448..463): entry e = (b, b') of w_up^T w_up
    int e = (blk - 448) * 256 + t;            // 0..4095
    int b = e >> 6, bp = e & 63;              // b wave-uniform, bp = lane (coalesced)
    float s = 0.f;
    for (int d = 0; d < EMBED; ++d) s += w_up[d * BN + b] * w_up[d * BN + bp];
    Mb[e] = f2bf(s);
}

// Persistent fused kernel. Per tile (16 rows): LN-stats + ||r||^2 (Phase A, f32 regs) ->
// dual GEMM1 (down-proj AND w_up^T x for the cross term, shared A-frag) -> GELU + cross
// reduce -> q = g^T (W^T W) g via 2 MFMA -> inv known BEFORE GEMM2 -> single-pass GEMM2
// (compute, scale, store; no accumulator array -> no spill). Next tile's x prefetched into
// regs right after B1 so HBM reads stay in flight through compute (latency fix).
// LDS ~52 KB -> 3 blocks/CU.
__global__ __launch_bounds__(256, 3) void fused_kernel(
    const float* __restrict__ x, const float* __restrict__ b_down,
    const float* __restrict__ b_up,
    const unsigned short* __restrict__ wdg, const unsigned short* __restrict__ wub,
    const unsigned short* __restrict__ wut, const unsigned short* __restrict__ Mb,
    const float* __restrict__ c1, const float* __restrict__ c2,
    const float* __restrict__ c3,
    float* __restrict__ out, int* __restrict__ cnt, int ntiles)
{
    __shared__ unsigned short xs[16 * XS_STRIDE];  // bf16(x): GEMM1 A-operand AND GEMM2 residual
    __shared__ unsigned short gs[16 * GS_STRIDE];  // bf16 gelu output [token][b]
    __shared__ float mean_s[16], rstd_s[16], sumsq_s[2][16];
    __shared__ int tile_s;

    const int tid  = threadIdx.x;
    const int wave = tid >> 6, lane = tid & 63;
    const int l16  = lane & 15, quad = lane >> 4;

    int tcur = blockIdx.x;                         // initial tile; queue starts at gridDim
    float4 v[4][6];                                // 4 rows/wave, 24 outstanding float4 loads
    {
        const long row0 = (long)tcur * 16;
        #pragma unroll
        for (int j = 0; j < 4; ++j) {
            const float4* xp = (const float4*)(x + (row0 + wave * 4 + j) * EMBED);
            #pragma unroll
            for (int k = 0; k < 6; ++k) v[j][k] = xp[lane + 64 * k];
        }
    }

    int parity = 0;
    for (;;) {
        // ---- Phase A: LN stats + ||x+b_up||^2 + stage bf16(x) ----
        #pragma unroll
        for (int j = 0; j < 4; ++j) {
            int lr = wave * 4 + j;
            float s = 0.f, ss = 0.f, rr = 0.f;
            #pragma unroll
            for (int k = 0; k < 6; ++k) {
                float4 bu = ((const float4*)b_up)[lane + 64 * k];  // L2-hot
                float4 c = v[j][k];
                s  += c.x + c.y + c.z + c.w;
                ss += c.x * c.x + c.y * c.y + c.z * c.z + c.w * c.w;
                float rx0 = c.x + bu.x, rx1 = c.y + bu.y, rx2 = c.z + bu.z, rx3 = c.w + bu.w;
                rr += rx0 * rx0 + rx1 * rx1 + rx2 * rx2 + rx3 * rx3;
            }
            #pragma unroll
            for (int m = 1; m < 64; m <<= 1) {
                s += __shfl_xor(s, m); ss += __shfl_xor(ss, m); rr += __shfl_xor(rr, m);
            }
            float mean = s * (1.f / EMBED);
            float var  = ss * (1.f / EMBED) - mean * mean;
            if (lane == 0) {
                mean_s[lr] = mean;
                rstd_s[lr] = rsqrtf(var + 1e-5f);
                sumsq_s[parity][lr] = rr;          // ||r||^2 is the sumsq base
            }
            #pragma unroll
            for (int k = 0; k < 6; ++k) {
                ushort4 p;
                p.x = f2bf(v[j][k].x); p.y = f2bf(v[j][k].y);
                p.z = f2bf(v[j][k].z); p.w = f2bf(v[j][k].w);
                *(ushort4*)(&xs[lr * XS_STRIDE + 4 * (lane + 64 * k)]) = p;
            }
        }
        if (tid == 0) tile_s = atomicAdd(cnt, 1);
        __syncthreads();  // B1: xs staged, tile_s broadcast

        const int tnext = tile_s;
        const bool have_next = (tnext < ntiles);
        if (have_next) {  // prefetch next tile while GEMM1/GEMM2 run
            const long row0 = (long)tnext * 16;
            #pragma unroll
            for (int j = 0; j < 4; ++j) {
                const float4* xp = (const float4*)(x + (row0 + wave * 4 + j) * EMBED);
                #pragma unroll
                for (int k = 0; k < 6; ++k) v[j][k] = xp[lane + 64 * k];
            }
        }

        // ---- GEMM1 (dual B): acc = x.(gamma*w_down)^T, acc2 = x.w_up (K=1536) ----
        f32x4 acc = {0.f, 0.f, 0.f, 0.f}, acc2 = {0.f, 0.f, 0.f, 0.f};
        {
            const unsigned short* arow = &xs[l16 * XS_STRIDE];                    // A[m=l16][k]
            const unsigned short* brow = wdg + (size_t)(wave * 16 + l16) * EMBED; // wdg[b][k]
            const unsigned short* trow = wut + (size_t)(wave * 16 + l16) * EMBED; // w_up^T[b][k]
            #pragma unroll 4
            for (int kk = 0; kk < 48; ++kk) {
                int ko = kk * 32 + quad * 8;
                short8 a = *(const short8*)(arow + ko);
                acc  = __builtin_amdgcn_mfma_f32_16x16x32_bf16(a, *(const short8*)(brow + ko), acc,  0, 0, 0);
                acc2 = __builtin_amdgcn_mfma_f32_16x16x32_bf16(a, *(const short8*)(trow + ko), acc2, 0, 0, 0);
            }
        }
        // epilogue: LN corrections + bias + exact GELU -> gs; cross term 2*(W^T r).g -> sumsq
        {
            int bg = wave * 16 + l16;  // D col = lane&15
            float c1v = c1[bg], c2v = c2[bg], bdv = b_down[bg], c3v = c3[bg];
            float crp[4];
            #pragma unroll
            for (int reg = 0; reg < 4; ++reg) {
                int r = quad * 4 + reg;  // D row = (lane>>4)*4 + reg (token)
                float rs = rstd_s[r];
                float vv = rs * acc[reg] - rs * mean_s[r] * c1v + c2v + bdv;
                float g = 0.5f * vv * (1.f + erff(vv * 0.70710678118654752f));
                gs[r * GS_STRIDE + bg] = f2bf(g);
                crp[reg] = (acc2[reg] + c3v) * g;   // (W^T x + W^T b_up)[b] * g[b], f32
            }
            #pragma unroll
            for (int reg = 0; reg < 4; ++reg) {     // sum over the 16 b's of this wave (quad-local)
                float cr = crp[reg];
                cr += __shfl_xor(cr, 1);
                cr += __shfl_xor(cr, 2);
                cr += __shfl_xor(cr, 4);
                cr += __shfl_xor(cr, 8);
                crp[reg] = cr;
            }
            if (l16 == 0) {
                #pragma unroll
                for (int reg = 0; reg < 4; ++reg)
                    atomicAdd(&sumsq_s[parity][quad * 4 + reg], 2.f * crp[reg]);
            }
        }
        __syncthreads();  // B2: gs ready (also drains prefetch; overlapped with GEMM1)

        // ---- q = g^T (W^T W) g via 2 MFMA reusing gb frags ----
        short8 gb0 = *(const short8*)(&gs[l16 * GS_STRIDE + quad * 8]);
        short8 gb1 = *(const short8*)(&gs[l16 * GS_STRIDE + 32 + quad * 8]);
        {
            const unsigned short* mrow = Mb + (wave * 16 + l16) * BN;  // Mb[b][b']
            short8 m0 = *(const short8*)(mrow + quad * 8);
            short8 m1 = *(const short8*)(mrow + 32 + quad * 8);
            f32x4 p = {0.f, 0.f, 0.f, 0.f};
            p = __builtin_amdgcn_mfma_f32_16x16x32_bf16(m0, gb0, p, 0, 0, 0);
            p = __builtin_amdgcn_mfma_f32_16x16x32_bf16(m1, gb1, p, 0, 0, 0);
            // p[reg] = (M g_tok)[b = wave*16+quad*4+reg], tok = l16
            ushort4 g4 = *(const ushort4*)(&gs[l16 * GS_STRIDE + wave * 16 + quad * 4]);
            float qp = p[0] * bf2f(g4.x) + p[1] * bf2f(g4.y)
                     + p[2] * bf2f(g4.z) + p[3] * bf2f(g4.w);
            qp += __shfl_xor(qp, 16);
            qp += __shfl_xor(qp, 32);
            if (lane < 16) atomicAdd(&sumsq_s[parity][l16], qp);
        }
        __syncthreads();  // B3: sumsq complete -> inv known BEFORE GEMM2

        // ---- GEMM2 single pass: c = w_up_tile.g^T + (x+b_up); store c*inv ----
        const float inv = 1.f / fmaxf(sqrtf(sumsq_s[parity][l16]), 1e-12f);
        float* orow = out + ((long)tcur * 16 + l16) * EMBED;
        const int dbase = wave * 384;
        #pragma unroll
        for (int t = 0; t < 24; ++t) {
            int d0 = dbase + t * 16;
            int dm = d0 + quad * 4;                                    // C rows: 4 consecutive d
            float4 bu = *(const float4*)(b_up + dm);
            ushort4 rx = *(const ushort4*)(&xs[l16 * XS_STRIDE + dm]); // residual: token l16
            f32x4 c;
            c[0] = bf2f(rx.x) + bu.x;
            c[1] = bf2f(rx.y) + bu.y;
            c[2] = bf2f(rx.z) + bu.z;
            c[3] = bf2f(rx.w) + bu.w;
            const unsigned short* wrow = wub + (size_t)(d0 + l16) * 64;  // A[m=l16][k]
            short8 a0 = *(const short8*)(wrow + quad * 8);
            short8 a1 = *(const short8*)(wrow + 32 + quad * 8);
            c = __builtin_amdgcn_mfma_f32_16x16x32_bf16(a0, gb0, c, 0, 0, 0);
            c = __builtin_amdgcn_mfma_f32_16x16x32_bf16(a1, gb1, c, 0, 0, 0);
            float4 o;
            o.x = c[0] * inv; o.y = c[1] * inv; o.z = c[2] * inv; o.w = c[3] * inv;
            *(float4*)(orow + dm) = o;   // 16 B/lane store
        }

        if (!have_next) break;
        tcur = tnext;
        parity ^= 1;
        __syncthreads();  // B4: all xs/gs readers done before next Phase A overwrites
    }
}

extern "C" void kernel_launch(void* const* d_in, const int* in_sizes, int n_in,
                              void* d_out, int out_size, void* d_ws, size_t ws_size,
                              hipStream_t stream)
{
    const float* x      = (const float*)d_in[0];
    const float* w_down = (const float*)d_in[1];
    const float* b_down = (const float*)d_in[2];
    const float* w_up   = (const float*)d_in[3];
    const float* b_up   = (const float*)d_in[4];
    const float* gamma  = (const float*)d_in[5];
    const float* beta   = (const float*)d_in[6];
    float* out = (float*)d_out;

    const int N = in_sizes[0] / EMBED;  // 32768, multiple of 16
    const int ntiles = N / 16;
    const int grid = ntiles < NT_GRID ? ntiles : NT_GRID;

    unsigned short* wdg = (unsigned short*)d_ws;
    unsigned short* wub = wdg + BN * EMBED;
    unsigned short* wut = wub + BN * EMBED;
    unsigned short* Mb  = wut + BN * EMBED;
    float* c1 = (float*)(Mb + BN * BN);
    float* c2 = c1 + BN;
    float* c3 = c2 + BN;
    int* cnt  = (int*)(c3 + BN);

    prep_kernel<<<448 + 16, 256, 0, stream>>>(w_down, w_up, gamma, beta, b_up,
                                              wdg, wub, wut, Mb, c1, c2, c3, cnt, grid);
    fused_kernel<<<grid, 256, 0, stream>>>(x, b_down, b_up, wdg, wub, wut, Mb,
                                           c1, c2, c3, out, cnt, ntiles);
}

// Round 4
// 520.554 us; speedup vs baseline: 1.4038x; 1.3843x over previous
//
#include <hip/hip_runtime.h>
#include <math.h>

#define EMBED 1536
#define BN 64
#define XS_STRIDE 1544   // shorts; row stride 3088 B -> 16B aligned (ds_read_b128 ok)
#define GS_STRIDE 80     // shorts; row stride 160 B -> 16B aligned
#define NT_GRID 768      // persistent blocks: 3 per CU (LDS-capped) x 256 CUs

typedef __attribute__((ext_vector_type(8))) short short8;
typedef __attribute__((ext_vector_type(4))) float f32x4;

__device__ inline unsigned short f2bf(float f) {
    union { float f; unsigned u; } c; c.f = f;
    unsigned u = c.u;
    return (unsigned short)((u + 0x7fffu + ((u >> 16) & 1u)) >> 16);
}
__device__ inline float bf2f(unsigned short h) {
    union { unsigned u; float f; } c; c.u = ((unsigned)h) << 16;
    return c.f;
}

// Prep: wdg=bf16(w_down*gamma), wub=bf16(w_up), wut=bf16(w_up^T), Mb=bf16(w_up^T w_up),
//       c1[b]=sum gamma*w_down, c2[b]=sum beta*w_down, c3[b]=sum w_up[:,b]*b_up, queue init.
__global__ void prep_kernel(const float* __restrict__ w_down, const float* __restrict__ w_up,
                            const float* __restrict__ gamma, const float* __restrict__ beta,
                            const float* __restrict__ b_up,
                            unsigned short* __restrict__ wdg, unsigned short* __restrict__ wub,
                            unsigned short* __restrict__ wut, unsigned short* __restrict__ Mb,
                            float* __restrict__ c1, float* __restrict__ c2,
                            float* __restrict__ c3, int* __restrict__ cnt, int cnt_init) {
    int blk = blockIdx.x;
    int t = threadIdx.x;
    if (blk == 0 && t == 0) *cnt = cnt_init;  // work-queue head (reset every launch)
    if (blk < 384) {
        int i = blk * 256 + t;                // < 64*1536
        int d = i % EMBED;
        wdg[i] = f2bf(w_down[i] * gamma[d]);  // fold LN gamma into down-weights
        wub[i] = f2bf(w_up[i]);
        int b2 = i / EMBED, d2 = i - b2 * EMBED;
        wut[i] = f2bf(w_up[d2 * BN + b2]);    // wut[b][d] = w_up[d][b]
        return;
    }
    if (blk < 448) {
        int b = blk - 384;                    // 0..63
        float s1 = 0.f, s2 = 0.f, s3 = 0.f;
        for (int d = t; d < EMBED; d += 256) {
            float w = w_down[b * EMBED + d];
            s1 += gamma[d] * w;
            s2 += beta[d] * w;
            s3 += w_up[d * BN + b] * b_up[d];
        }
        #pragma unroll
        for (int m = 1; m < 64; m <<= 1) {
            s1 += __shfl_xor(s1, m); s2 += __shfl_xor(s2, m); s3 += __shfl_xor(s3, m);
        }
        __shared__ float r1[4], r2[4], r3[4];
        int wave = t >> 6, lane = t & 63;
        if (lane == 0) { r1[wave] = s1; r2[wave] = s2; r3[wave] = s3; }
        __syncthreads();
        if (t == 0) {
            c1[b] = r1[0] + r1[1] + r1[2] + r1[3];
            c2[b] = r2[0] + r2[1] + r2[2] + r2[3];
            c3[b] = r3[0] + r3[1] + r3[2] + r3[3];
        }
        return;
    }
    // Mb blocks (448..463): entry e = (b, b') of w_up^T w_up
    int e = (blk - 448) * 256 + t;            // 0..4095
    int b = e >> 6, bp = e & 63;              // b wave-uniform, bp = lane (coalesced)
    float s = 0.f;
    for (int d = 0; d < EMBED; ++d) s += w_up[d * BN + b] * w_up[d * BN + bp];
    Mb[e] = f2bf(s);
}

// Persistent fused kernel. Per tile (16 rows): LN-stats + ||r||^2 (Phase A, f32 regs) ->
// dual GEMM1 (down-proj AND w_up^T x for the cross term, shared A-frag) -> GELU + cross
// reduce -> q = g^T (W^T W) g via 2 MFMA -> inv known BEFORE GEMM2 -> single-pass GEMM2.
// Next tile's x prefetched into regs right after B1 so HBM reads stay in flight.
// launch_bounds(256,1): empirically the allocator budgets 512/(2*arg) regs for 256-thread
// blocks; arg=3 gave an 85-reg cap -> v[4][6] spilled to scratch (+330 MB HBM each way,
// rounds 2-3). arg=1 -> cap 256, live set ~160 fits. LDS 52 KB still caps 3 blocks/CU.
__global__ __launch_bounds__(256, 1) void fused_kernel(
    const float* __restrict__ x, const float* __restrict__ b_down,
    const float* __restrict__ b_up,
    const unsigned short* __restrict__ wdg, const unsigned short* __restrict__ wub,
    const unsigned short* __restrict__ wut, const unsigned short* __restrict__ Mb,
    const float* __restrict__ c1, const float* __restrict__ c2,
    const float* __restrict__ c3,
    float* __restrict__ out, int* __restrict__ cnt, int ntiles)
{
    __shared__ unsigned short xs[16 * XS_STRIDE];  // bf16(x): GEMM1 A-operand AND GEMM2 residual
    __shared__ unsigned short gs[16 * GS_STRIDE];  // bf16 gelu output [token][b]
    __shared__ float mean_s[16], rstd_s[16], sumsq_s[2][16];
    __shared__ int tile_s;

    const int tid  = threadIdx.x;
    const int wave = tid >> 6, lane = tid & 63;
    const int l16  = lane & 15, quad = lane >> 4;

    int tcur = blockIdx.x;                         // initial tile; queue starts at gridDim
    float4 v[4][6];                                // 4 rows/wave, 24 outstanding float4 loads
    {
        const long row0 = (long)tcur * 16;
        #pragma unroll
        for (int j = 0; j < 4; ++j) {
            const float4* xp = (const float4*)(x + (row0 + wave * 4 + j) * EMBED);
            #pragma unroll
            for (int k = 0; k < 6; ++k) v[j][k] = xp[lane + 64 * k];
        }
    }

    int parity = 0;
    for (;;) {
        // ---- Phase A: LN stats + ||x+b_up||^2 + stage bf16(x) ----
        #pragma unroll
        for (int j = 0; j < 4; ++j) {
            int lr = wave * 4 + j;
            float s = 0.f, ss = 0.f, rr = 0.f;
            #pragma unroll
            for (int k = 0; k < 6; ++k) {
                float4 bu = ((const float4*)b_up)[lane + 64 * k];  // L2-hot
                float4 c = v[j][k];
                s  += c.x + c.y + c.z + c.w;
                ss += c.x * c.x + c.y * c.y + c.z * c.z + c.w * c.w;
                float rx0 = c.x + bu.x, rx1 = c.y + bu.y, rx2 = c.z + bu.z, rx3 = c.w + bu.w;
                rr += rx0 * rx0 + rx1 * rx1 + rx2 * rx2 + rx3 * rx3;
            }
            #pragma unroll
            for (int m = 1; m < 64; m <<= 1) {
                s += __shfl_xor(s, m); ss += __shfl_xor(ss, m); rr += __shfl_xor(rr, m);
            }
            float mean = s * (1.f / EMBED);
            float var  = ss * (1.f / EMBED) - mean * mean;
            if (lane == 0) {
                mean_s[lr] = mean;
                rstd_s[lr] = rsqrtf(var + 1e-5f);
                sumsq_s[parity][lr] = rr;          // ||r||^2 is the sumsq base
            }
            #pragma unroll
            for (int k = 0; k < 6; ++k) {
                ushort4 p;
                p.x = f2bf(v[j][k].x); p.y = f2bf(v[j][k].y);
                p.z = f2bf(v[j][k].z); p.w = f2bf(v[j][k].w);
                *(ushort4*)(&xs[lr * XS_STRIDE + 4 * (lane + 64 * k)]) = p;
            }
        }
        if (tid == 0) tile_s = atomicAdd(cnt, 1);
        __syncthreads();  // B1: xs staged, tile_s broadcast

        const int tnext = tile_s;
        const bool have_next = (tnext < ntiles);
        if (have_next) {  // prefetch next tile while GEMM1/GEMM2 run
            const long row0 = (long)tnext * 16;
            #pragma unroll
            for (int j = 0; j < 4; ++j) {
                const float4* xp = (const float4*)(x + (row0 + wave * 4 + j) * EMBED);
                #pragma unroll
                for (int k = 0; k < 6; ++k) v[j][k] = xp[lane + 64 * k];
            }
        }

        // ---- GEMM1 (dual B): acc = x.(gamma*w_down)^T, acc2 = x.w_up (K=1536) ----
        f32x4 acc = {0.f, 0.f, 0.f, 0.f}, acc2 = {0.f, 0.f, 0.f, 0.f};
        {
            const unsigned short* arow = &xs[l16 * XS_STRIDE];                    // A[m=l16][k]
            const unsigned short* brow = wdg + (size_t)(wave * 16 + l16) * EMBED; // wdg[b][k]
            const unsigned short* trow = wut + (size_t)(wave * 16 + l16) * EMBED; // w_up^T[b][k]
            #pragma unroll 4
            for (int kk = 0; kk < 48; ++kk) {
                int ko = kk * 32 + quad * 8;
                short8 a = *(const short8*)(arow + ko);
                acc  = __builtin_amdgcn_mfma_f32_16x16x32_bf16(a, *(const short8*)(brow + ko), acc,  0, 0, 0);
                acc2 = __builtin_amdgcn_mfma_f32_16x16x32_bf16(a, *(const short8*)(trow + ko), acc2, 0, 0, 0);
            }
        }
        // epilogue: LN corrections + bias + exact GELU -> gs; cross term 2*(W^T r).g -> sumsq
        {
            int bg = wave * 16 + l16;  // D col = lane&15
            float c1v = c1[bg], c2v = c2[bg], bdv = b_down[bg], c3v = c3[bg];
            float crp[4];
            #pragma unroll
            for (int reg = 0; reg < 4; ++reg) {
                int r = quad * 4 + reg;  // D row = (lane>>4)*4 + reg (token)
                float rs = rstd_s[r];
                float vv = rs * acc[reg] - rs * mean_s[r] * c1v + c2v + bdv;
                float g = 0.5f * vv * (1.f + erff(vv * 0.70710678118654752f));
                gs[r * GS_STRIDE + bg] = f2bf(g);
                crp[reg] = (acc2[reg] + c3v) * g;   // (W^T x + W^T b_up)[b] * g[b], f32
            }
            #pragma unroll
            for (int reg = 0; reg < 4; ++reg) {     // sum over the 16 b's of this wave (quad-local)
                float cr = crp[reg];
                cr += __shfl_xor(cr, 1);
                cr += __shfl_xor(cr, 2);
                cr += __shfl_xor(cr, 4);
                cr += __shfl_xor(cr, 8);
                crp[reg] = cr;
            }
            if (l16 == 0) {
                #pragma unroll
                for (int reg = 0; reg < 4; ++reg)
                    atomicAdd(&sumsq_s[parity][quad * 4 + reg], 2.f * crp[reg]);
            }
        }
        __syncthreads();  // B2: gs ready (also drains prefetch; overlapped with GEMM1)

        // ---- q = g^T (W^T W) g via 2 MFMA reusing gb frags ----
        short8 gb0 = *(const short8*)(&gs[l16 * GS_STRIDE + quad * 8]);
        short8 gb1 = *(const short8*)(&gs[l16 * GS_STRIDE + 32 + quad * 8]);
        {
            const unsigned short* mrow = Mb + (wave * 16 + l16) * BN;  // Mb[b][b']
            short8 m0 = *(const short8*)(mrow + quad * 8);
            short8 m1 = *(const short8*)(mrow + 32 + quad * 8);
            f32x4 p = {0.f, 0.f, 0.f, 0.f};
            p = __builtin_amdgcn_mfma_f32_16x16x32_bf16(m0, gb0, p, 0, 0, 0);
            p = __builtin_amdgcn_mfma_f32_16x16x32_bf16(m1, gb1, p, 0, 0, 0);
            // p[reg] = (M g_tok)[b = wave*16+quad*4+reg], tok = l16
            ushort4 g4 = *(const ushort4*)(&gs[l16 * GS_STRIDE + wave * 16 + quad * 4]);
            float qp = p[0] * bf2f(g4.x) + p[1] * bf2f(g4.y)
                     + p[2] * bf2f(g4.z) + p[3] * bf2f(g4.w);
            qp += __shfl_xor(qp, 16);
            qp += __shfl_xor(qp, 32);
            if (lane < 16) atomicAdd(&sumsq_s[parity][l16], qp);
        }
        __syncthreads();  // B3: sumsq complete -> inv known BEFORE GEMM2

        // ---- GEMM2 single pass: c = w_up_tile.g^T + (x+b_up); store c*inv ----
        const float inv = 1.f / fmaxf(sqrtf(sumsq_s[parity][l16]), 1e-12f);
        float* orow = out + ((long)tcur * 16 + l16) * EMBED;
        const int dbase = wave * 384;
        #pragma unroll 4
        for (int t = 0; t < 24; ++t) {
            int d0 = dbase + t * 16;
            int dm = d0 + quad * 4;                                    // C rows: 4 consecutive d
            float4 bu = *(const float4*)(b_up + dm);
            ushort4 rx = *(const ushort4*)(&xs[l16 * XS_STRIDE + dm]); // residual: token l16
            f32x4 c;
            c[0] = bf2f(rx.x) + bu.x;
            c[1] = bf2f(rx.y) + bu.y;
            c[2] = bf2f(rx.z) + bu.z;
            c[3] = bf2f(rx.w) + bu.w;
            const unsigned short* wrow = wub + (size_t)(d0 + l16) * 64;  // A[m=l16][k]
            short8 a0 = *(const short8*)(wrow + quad * 8);
            short8 a1 = *(const short8*)(wrow + 32 + quad * 8);
            c = __builtin_amdgcn_mfma_f32_16x16x32_bf16(a0, gb0, c, 0, 0, 0);
            c = __builtin_amdgcn_mfma_f32_16x16x32_bf16(a1, gb1, c, 0, 0, 0);
            float4 o;
            o.x = c[0] * inv; o.y = c[1] * inv; o.z = c[2] * inv; o.w = c[3] * inv;
            *(float4*)(orow + dm) = o;   // 16 B/lane store
        }

        if (!have_next) break;
        tcur = tnext;
        parity ^= 1;
        __syncthreads();  // B4: all xs/gs readers done before next Phase A overwrites
    }
}

extern "C" void kernel_launch(void* const* d_in, const int* in_sizes, int n_in,
                              void* d_out, int out_size, void* d_ws, size_t ws_size,
                              hipStream_t stream)
{
    const float* x      = (const float*)d_in[0];
    const float* w_down = (const float*)d_in[1];
    const float* b_down = (const float*)d_in[2];
    const float* w_up   = (const float*)d_in[3];
    const float* b_up   = (const float*)d_in[4];
    const float* gamma  = (const float*)d_in[5];
    const float* beta   = (const float*)d_in[6];
    float* out = (float*)d_out;

    const int N = in_sizes[0] / EMBED;  // 32768, multiple of 16
    const int ntiles = N / 16;
    const int grid = ntiles < NT_GRID ? ntiles : NT_GRID;

    unsigned short* wdg = (unsigned short*)d_ws;
    unsigned short* wub = wdg + BN * EMBED;
    unsigned short* wut = wub + BN * EMBED;
    unsigned short* Mb  = wut + BN * EMBED;
    float* c1 = (float*)(Mb + BN * BN);
    float* c2 = c1 + BN;
    float* c3 = c2 + BN;
    int* cnt  = (int*)(c3 + BN);

    prep_kernel<<<448 + 16, 256, 0, stream>>>(w_down, w_up, gamma, beta, b_up,
                                              wdg, wub, wut, Mb, c1, c2, c3, cnt, grid);
    fused_kernel<<<grid, 256, 0, stream>>>(x, b_down, b_up, wdg, wub, wut, Mb,
                                           c1, c2, c3, out, cnt, ntiles);
}